// Round 16
// baseline (283.943 us; speedup 1.0000x reference)
//
#include <hip/hip_runtime.h>

typedef __attribute__((ext_vector_type(8))) short bf16x8;
typedef __attribute__((ext_vector_type(4))) float f32x4;
typedef __attribute__((ext_vector_type(4))) unsigned short u16x4;

#define DEV static __device__ __forceinline__

DEV float bf2f(unsigned short u) {
  union { unsigned int i; float f; } v; v.i = ((unsigned int)u) << 16; return v.f;
}
DEV unsigned short f2bf(float f) {
  unsigned int x = __float_as_uint(f);
  x += 0x7fffu + ((x >> 16) & 1u);   // round-to-nearest-even
  return (unsigned short)(x >> 16);
}
DEV f32x4 mfma16(bf16x8 a, bf16x8 b, f32x4 c) {
  return __builtin_amdgcn_mfma_f32_16x16x32_bf16(a, b, c, 0, 0, 0);
}
DEV void gload_lds16(const void* g, void* l) {
  __builtin_amdgcn_global_load_lds(
      (const __attribute__((address_space(1))) unsigned int*)g,
      (__attribute__((address_space(3))) unsigned int*)l, 16, 0, 0);
}

// ---------------------------------------------------------------- tables
__global__ void build_tables(float* __restrict__ ct, float* __restrict__ st) {
  int idx = blockIdx.x * 256 + threadIdx.x;   // 2048*64 = 131072
  int i = idx & 63, t = idx >> 6;
  float f = powf(10000.0f, -(float)i * (1.0f / 64.0f));
  float a = (float)t * f;
  ct[idx] = cosf(a);
  st[idx] = sinf(a);
}

// ---------------------------------------------------------------- f32 -> bf16 cast (x4)
__global__ void cast_bf(const float* __restrict__ in, unsigned short* __restrict__ out, int n4) {
  int idx = blockIdx.x * 256 + threadIdx.x;
  if (idx >= n4) return;
  f32x4 v = *(const f32x4*)(in + (size_t)idx * 4);
  u16x4 o;
  #pragma unroll
  for (int j = 0; j < 4; ++j) o[j] = f2bf(v[j]);
  *(u16x4*)(out + (size_t)idx * 4) = o;
}

// ---------------------------------------------------------------- depthwise causal conv (K=3) + cast
__global__ void conv_cast(const float* __restrict__ x, const float* __restrict__ w,
                          unsigned short* __restrict__ out) {
  int idx = blockIdx.x * 256 + threadIdx.x;   // B*T*C/4 = 2,097,152
  int c4 = idx & 511, t = (idx >> 9) & 2047;  // b = idx >> 20
  int c = c4 * 4;
  const float* xp = x + (size_t)(idx >> 20) * 2048 * 2048 + (size_t)t * 2048 + c;
  f32x4 v2 = *(const f32x4*)xp;
  f32x4 v1 = {0.f, 0.f, 0.f, 0.f}, v0 = {0.f, 0.f, 0.f, 0.f};
  if (t >= 1) v1 = *(const f32x4*)(xp - 2048);
  if (t >= 2) v0 = *(const f32x4*)(xp - 4096);
  u16x4 o;
  #pragma unroll
  for (int j = 0; j < 4; ++j) {
    float val = v0[j] * w[(c + j) * 3 + 0] + v1[j] * w[(c + j) * 3 + 1] + v2[j] * w[(c + j) * 3 + 2];
    o[j] = f2bf(val);
  }
  *(u16x4*)(idx * 4 + out) = o;
}

// ---------------------------------------------------------------- BT GEMM, 2-phase + counted vmcnt (r6 loop)
// MODE 0: plain f32 C output (proj). MODE 1: fused RoPE(Q,K)+V-transpose epilogue.
// V-blocks store the acc tile TRANSPOSED into LDS so the Vt write reads b128
// (16 vector reads/thread instead of 128 scalar gathers).
template <int MFRAG, int NFRAG, int MODE>   // BM=MFRAG*32, BN=NFRAG*64
__global__ __launch_bounds__(512, 2) void gemm2p(const unsigned short* __restrict__ A,
                                                 const unsigned short* __restrict__ Bw,
                                                 void* __restrict__ Cp, int M, int N, int K,
                                                 const float* __restrict__ ct,
                                                 const float* __restrict__ st,
                                                 unsigned short* __restrict__ Qo,
                                                 unsigned short* __restrict__ Ko,
                                                 unsigned short* __restrict__ Vt) {
  constexpr int BM = MFRAG * 32;
  constexpr int BN = NFRAG * 64;
  constexpr int ALD = BM / 128;
  constexpr int BLD = BN / 128;
  constexpr int STEADY = 2 * (ALD + BLD);
  constexpr int HALF = ALD + BLD;
  __shared__ __align__(16) unsigned short smem[2 * 2 * (BM + BN) * 32];
  unsigned short* AsB = smem;                       // [2buf][2kh][BM*32]
  unsigned short* BsB = smem + 2 * 2 * BM * 32;     // [2buf][2kh][BN*32]
  const int tid = threadIdx.x;
  const int w = tid >> 6, l = tid & 63;
  const int lr = l & 15, lg = l >> 4;
  const int wm = w >> 2, wn = w & 3;
  const int nbx = N / BN, nby = M / BM;
  const int nwg = nbx * nby;
  const int bid = blockIdx.x;
  const int wg = (bid & 7) * (nwg >> 3) + (bid >> 3);
  const int bx = wg / nby, by = wg % nby;
  const int m0 = by * BM, n0 = bx * BN;

  int aOff[ALD], bOff[BLD];
  #pragma unroll
  for (int it = 0; it < ALD; ++it) {
    int q = it * 512 + tid, row = q >> 2, cp = q & 3;
    aOff[it] = (m0 + row) * K + ((cp ^ ((row >> 1) & 3)) * 8);
  }
  #pragma unroll
  for (int it = 0; it < BLD; ++it) {
    int q = it * 512 + tid, row = q >> 2, cp = q & 3;
    bOff[it] = (n0 + row) * K + ((cp ^ ((row >> 1) & 3)) * 8);
  }
  const int dstW = w * 512;

  int aRd[MFRAG], bRd[NFRAG];
  #pragma unroll
  for (int m = 0; m < MFRAG; ++m) {
    int R = wm * (MFRAG * 16) + m * 16 + lr;
    aRd[m] = R * 32 + ((lg ^ ((R >> 1) & 3)) * 8);
  }
  #pragma unroll
  for (int n = 0; n < NFRAG; ++n) {
    int R = wn * (NFRAG * 16) + n * 16 + lr;
    bRd[n] = R * 32 + ((lg ^ ((R >> 1) & 3)) * 8);
  }

  auto stageA = [&](int tt, int kh) {
    const unsigned short* s = A + (size_t)(tt * 64 + kh * 32);
    unsigned short* d = AsB + ((tt & 1) * 2 + kh) * (BM * 32) + dstW;
    #pragma unroll
    for (int it = 0; it < ALD; ++it) gload_lds16(s + aOff[it], d + it * 4096);
  };
  auto stageB = [&](int tt, int kh) {
    const unsigned short* s = Bw + (size_t)(tt * 64 + kh * 32);
    unsigned short* d = BsB + ((tt & 1) * 2 + kh) * (BN * 32) + dstW;
    #pragma unroll
    for (int it = 0; it < BLD; ++it) gload_lds16(s + bOff[it], d + it * 4096);
  };
  #define WAIT_STEADY do { if constexpr (STEADY == 8) asm volatile("s_waitcnt vmcnt(8)" ::: "memory"); \
                           else asm volatile("s_waitcnt vmcnt(6)" ::: "memory"); } while (0)
  #define WAIT_HALF   do { if constexpr (HALF == 4) asm volatile("s_waitcnt vmcnt(4)" ::: "memory"); \
                           else asm volatile("s_waitcnt vmcnt(3)" ::: "memory"); } while (0)
  #define WAIT_ZERO   asm volatile("s_waitcnt vmcnt(0)" ::: "memory")

  #define PH(BUF, KH, STAGE_STMT, WAIT_STMT)                              \
  {                                                                       \
    const unsigned short* Ab = AsB + ((BUF) * 2 + (KH)) * (BM * 32);      \
    const unsigned short* Bb = BsB + ((BUF) * 2 + (KH)) * (BN * 32);      \
    bf16x8 aF[MFRAG], bF[NFRAG];                                          \
    _Pragma("unroll") for (int m = 0; m < MFRAG; ++m)                     \
        aF[m] = *(const bf16x8*)(Ab + aRd[m]);                            \
    _Pragma("unroll") for (int n = 0; n < NFRAG; ++n)                     \
        bF[n] = *(const bf16x8*)(Bb + bRd[n]);                            \
    STAGE_STMT;                                                           \
    __builtin_amdgcn_sched_barrier(0);                                    \
    __builtin_amdgcn_s_barrier();                                         \
    __builtin_amdgcn_sched_barrier(0);                                    \
    __builtin_amdgcn_s_setprio(1);                                        \
    _Pragma("unroll") for (int m = 0; m < MFRAG; ++m)                     \
      _Pragma("unroll") for (int n = 0; n < NFRAG; ++n)                   \
          acc[m][n] = mfma16(aF[m], bF[n], acc[m][n]);                    \
    __builtin_amdgcn_s_setprio(0);                                        \
    WAIT_STMT;                                                            \
    __builtin_amdgcn_sched_barrier(0);                                    \
    __builtin_amdgcn_s_barrier();                                         \
    __builtin_amdgcn_sched_barrier(0);                                    \
  }

  f32x4 acc[MFRAG][NFRAG] = {};
  const int NT = K >> 6;
  stageA(0, 0); stageB(0, 0);
  stageA(0, 1); stageB(0, 1);
  stageA(1, 0); stageB(1, 0);
  __builtin_amdgcn_sched_barrier(0);
  WAIT_STEADY;
  __builtin_amdgcn_s_barrier();
  __builtin_amdgcn_sched_barrier(0);

  int t = 0;
  for (; t + 2 < NT; ++t) {
    PH(t & 1, 0, { stageA(t + 1, 1); stageB(t + 1, 1); }, WAIT_STEADY);
    PH(t & 1, 1, { stageA(t + 2, 0); stageB(t + 2, 0); }, WAIT_STEADY);
  }
  PH(t & 1, 0, { stageA(t + 1, 1); stageB(t + 1, 1); }, WAIT_STEADY);
  PH(t & 1, 1, {}, WAIT_HALF);
  ++t;
  PH(t & 1, 0, {}, WAIT_ZERO);
  PH(t & 1, 1, {}, {});
  #undef PH
  #undef WAIT_STEADY
  #undef WAIT_HALF
  #undef WAIT_ZERO

  if constexpr (MODE == 0) {
    // plain f32 epilogue (proj)
    #pragma unroll
    for (int m = 0; m < MFRAG; ++m)
      #pragma unroll
      for (int r = 0; r < 4; ++r) {
        int row = m0 + wm * (MFRAG * 16) + m * 16 + lg * 4 + r;
        #pragma unroll
        for (int n = 0; n < NFRAG; ++n) {
          int col = n0 + wn * (NFRAG * 16) + n * 16 + lr;
          ((float*)Cp)[(size_t)row * N + col] = acc[m][n][r];
        }
      }
  } else {
    // fused RoPE + V-transpose epilogue. 256x256 tile == full staging LDS.
    static_assert(MODE != 1 || (BM == 256 && BN == 256), "fused epilogue needs 256x256");
    auto tadr = [&](int row, int col) {
      return row * 256 + ((((col >> 3) ^ (row & 7))) << 3) + (col & 7);
    };
    const int sec = n0 >> 11;              // 0=q, 1=k, 2=v
    const int hbase = (n0 & 2047) >> 7;    // head base (2 heads per tile)
    const int bb = m0 >> 11;               // batch
    const int t0a = m0 & 2047;             // t base
    // acc -> swizzled bf16 tile; V-blocks store TRANSPOSED (tile[d][t])
    #pragma unroll
    for (int m = 0; m < MFRAG; ++m)
      #pragma unroll
      for (int r = 0; r < 4; ++r) {
        int row = wm * (MFRAG * 16) + m * 16 + lg * 4 + r;
        #pragma unroll
        for (int n = 0; n < NFRAG; ++n) {
          int col = wn * (NFRAG * 16) + n * 16 + lr;
          if (sec == 2) smem[tadr(col, row)] = f2bf(acc[m][n][r]);
          else          smem[tadr(row, col)] = f2bf(acc[m][n][r]);
        }
      }
    __syncthreads();
    if (sec < 2) {
      unsigned short* outp = (sec == 0) ? Qo : Ko;
      const int c8 = (tid & 31) * 8;       // col base (mult of 8)
      const int rb = tid >> 5;             // 0..15
      const int dloc = c8 & 127;           // d base within head
      const int hh = hbase + (c8 >> 7);
      const bool lowh = dloc < 64;
      const int ib = dloc & 63;
      unsigned short* obase = outp + ((size_t)(bb * 16 + hh) * 2048) * 128;
      #pragma unroll
      for (int j = 0; j < 16; ++j) {
        int row = rb * 16 + j;
        int tt2 = t0a + row;
        bf16x8 self = *(const bf16x8*)(smem + tadr(row, c8));
        bf16x8 part = *(const bf16x8*)(smem + tadr(row, c8 ^ 64));
        const float* cp2 = ct + tt2 * 64 + ib;
        const float* sp2 = st + tt2 * 64 + ib;
        bf16x8 o8;
        #pragma unroll
        for (int e = 0; e < 8; ++e) {
          float a = bf2f(((const unsigned short*)&self)[e]);
          float p = bf2f(((const unsigned short*)&part)[e]);
          float cz = cp2[e], sz = sp2[e];
          ((unsigned short*)&o8)[e] = f2bf(lowh ? (a * cz - p * sz) : (a * cz + p * sz));
        }
        *(bf16x8*)(obase + (size_t)tt2 * 128 + dloc) = o8;
      }
    } else {
      // tile is [d][t]: vectorized b128 reads along t
      const int c = tid >> 1, half = tid & 1;     // c = d-in-tile 0..255
      const int dd = c & 127, hh = hbase + (c >> 7);
      unsigned short* dst = Vt + ((size_t)(bb * 16 + hh) * 128 + dd) * 2048 + t0a + half * 128;
      #pragma unroll
      for (int j = 0; j < 16; ++j) {
        int tt3 = half * 128 + j * 8;
        bf16x8 v8 = *(const bf16x8*)(smem + tadr(c, tt3));
        *(bf16x8*)(dst + j * 8) = v8;
      }
    }
  }
}

// ---------------------------------------------------------------- flash attention (causal), swapped QK^T (r14 form)
// defer-max, spill-free: ONE shared exp2 loop; guard wraps only the rescale block.
// grid: (32 bh, 32 qtile) ; block 256 = 4 waves x 16 q-rows ; KV tile 64
__global__ __launch_bounds__(256, 4) void attn_fwd(const unsigned short* __restrict__ Q,
                                                   const unsigned short* __restrict__ K,
                                                   const unsigned short* __restrict__ Vt,
                                                   unsigned short* __restrict__ Y) {
  const int T = 2048, D = 128, C = 2048;
  __shared__ __align__(16) unsigned short Ks[64 * 128];   // [kv][cc ^ (kv&7)]
  __shared__ __align__(16) unsigned short Vs[128 * 64];   // [d][cc ^ (d&7)]
  __shared__ __align__(16) unsigned short Pl[4][16 * 64]; // per-wave [q][cc ^ (q&7)]
  const int tid = threadIdx.x;
  const int w = tid >> 6, l = tid & 63;
  const int lr = l & 15, lg = l >> 4;
  const int bh = blockIdx.x;
  const int qi = (int)gridDim.y - 1 - (int)blockIdx.y;    // longest-first
  const int qbase = qi * 64;
  const size_t base = (size_t)bh * T * D;

  bf16x8 qf[4];
  {
    const unsigned short* qp = Q + base + (size_t)(qbase + w * 16 + lr) * D + lg * 8;
    #pragma unroll
    for (int d = 0; d < 4; ++d) qf[d] = *(const bf16x8*)(qp + d * 32);
  }
  int kSrc[4], vSrc[4], ldsDst[4];
  #pragma unroll
  for (int it = 0; it < 4; ++it) {
    int c = it * 256 + tid;
    int krow = c >> 4, kdc = c & 15;
    kSrc[it] = krow * D + ((kdc ^ (krow & 7)) * 8);
    int vd = c >> 3, vcc = c & 7;
    vSrc[it] = vd * T + ((vcc ^ (vd & 7)) * 8);
    ldsDst[it] = (it * 256 + w * 64) * 8;
  }
  f32x4 ao[8] = {};
  float mrun = -3.0e38f, lrun = 0.0f;
  const float cs = 0.08838834764831845f * 1.4426950408889634f;  // 1/sqrt(128) * log2(e)
  const float THR = 8.0f / cs;                                  // growth bound: p <= 2^8
  const int q_abs = qbase + w * 16 + lr;

  for (int kt = 0; kt <= qi; ++kt) {
    const int kv0 = kt * 64;
    #pragma unroll
    for (int it = 0; it < 4; ++it) {
      gload_lds16(K + base + (size_t)kv0 * D + kSrc[it], Ks + ldsDst[it]);
      gload_lds16(Vt + base + kv0 + vSrc[it], Vs + ldsDst[it]);
    }
    __syncthreads();
    f32x4 s4[4] = {};
    __builtin_amdgcn_s_setprio(1);
    #pragma unroll
    for (int n = 0; n < 4; ++n) {
      int row = n * 16 + lr;
      #pragma unroll
      for (int d = 0; d < 4; ++d) {
        bf16x8 kf = *(const bf16x8*)(Ks + row * 128 + (((d * 4 + lg) ^ (lr & 7)) * 8));
        s4[n] = mfma16(kf, qf[d], s4[n]);
      }
    }
    __builtin_amdgcn_s_setprio(0);
    if (kt == qi) {
      #pragma unroll
      for (int n = 0; n < 4; ++n)
        #pragma unroll
        for (int r = 0; r < 4; ++r)
          if (kv0 + n * 16 + lg * 4 + r > q_abs) s4[n][r] = -3.0e38f;
    }
    float mx = -3.0e38f;
    #pragma unroll
    for (int n = 0; n < 4; ++n)
      #pragma unroll
      for (int r = 0; r < 4; ++r) mx = fmaxf(mx, s4[n][r]);
    mx = fmaxf(mx, __shfl_xor(mx, 16, 64));
    mx = fmaxf(mx, __shfl_xor(mx, 32, 64));
    if (!__all(mx - mrun <= THR)) {
      float mnew = fmaxf(mrun, mx);
      float fac = exp2f((mrun - mnew) * cs);
      mrun = mnew;
      lrun *= fac;
      float fr[4];
      #pragma unroll
      for (int r = 0; r < 4; ++r) fr[r] = __shfl(fac, (l & 48) | (lg * 4 + r), 64);
      #pragma unroll
      for (int n8 = 0; n8 < 8; ++n8)
        #pragma unroll
        for (int r = 0; r < 4; ++r) ao[n8][r] *= fr[r];
    }
    float sum = 0.0f;
    #pragma unroll
    for (int n = 0; n < 4; ++n)
      #pragma unroll
      for (int r = 0; r < 4; ++r) {
        float p = exp2f((s4[n][r] - mrun) * cs);
        s4[n][r] = p;
        sum += p;
      }
    sum += __shfl_xor(sum, 16, 64);
    sum += __shfl_xor(sum, 32, 64);
    lrun += sum;
    unsigned short* pw = (unsigned short*)Pl[w];
    #pragma unroll
    for (int n = 0; n < 4; ++n)
      #pragma unroll
      for (int i = 0; i < 2; ++i) {
        unsigned int pk = (unsigned int)f2bf(s4[n][2 * i]) |
                          ((unsigned int)f2bf(s4[n][2 * i + 1]) << 16);
        int kv = n * 16 + lg * 4 + 2 * i;
        *(unsigned int*)(pw + lr * 64 + (((kv >> 3) ^ (lr & 7)) * 8) + (kv & 7)) = pk;
      }
    __builtin_amdgcn_s_setprio(1);
    #pragma unroll
    for (int ks = 0; ks < 2; ++ks) {
      bf16x8 pa = *(const bf16x8*)(pw + lr * 64 + (((ks * 4 + lg) ^ (lr & 7)) * 8));
      #pragma unroll
      for (int n = 0; n < 8; ++n) {
        int row = n * 16 + lr;
        bf16x8 vb = *(const bf16x8*)(Vs + row * 64 + (((ks * 4 + lg) ^ (lr & 7)) * 8));
        ao[n] = mfma16(pa, vb, ao[n]);
      }
    }
    __builtin_amdgcn_s_setprio(0);
    __syncthreads();
  }
  const int b = bh >> 4, h = bh & 15;
  #pragma unroll
  for (int r = 0; r < 4; ++r) {
    float lsum = __shfl(lrun, (l & 48) | (lg * 4 + r), 64);
    float inv = 1.0f / lsum;
    int t = qbase + w * 16 + lg * 4 + r;
    unsigned short* dst = Y + ((size_t)b * T + t) * C + h * D;
    #pragma unroll
    for (int n = 0; n < 8; ++n) dst[n * 16 + lr] = f2bf(ao[n][r] * inv);
  }
}

// ---------------------------------------------------------------- launch
extern "C" void kernel_launch(void* const* d_in, const int* in_sizes, int n_in,
                              void* d_out, int out_size, void* d_ws, size_t ws_size,
                              hipStream_t stream) {
  const float* x      = (const float*)d_in[0];
  const float* conv_w = (const float*)d_in[1];
  const float* w_attn = (const float*)d_in[2];
  const float* w_proj = (const float*)d_in[3];
  float* out = (float*)d_out;
  char* ws = (char*)d_ws;

  unsigned short* qb   = (unsigned short*)(ws + 50331648);      // 16,777,216
  unsigned short* kb   = (unsigned short*)(ws + 67108864);      // 16,777,216
  unsigned short* vt   = (unsigned short*)(ws + 83886080);      // 16,777,216 (V transposed)
  unsigned short* xcy  = (unsigned short*)(ws + 100663296);     // 16,777,216 (xconv, then y)
  unsigned short* wbuf = (unsigned short*)(ws + 117440512);     // 25,165,824
  float* ctab = (float*)(ws + 142606336);                       // 524,288
  float* stab = (float*)(ws + 143130624);                       // 524,288

  build_tables<<<512, 256, 0, stream>>>(ctab, stab);
  cast_bf<<<12288, 256, 0, stream>>>(w_attn, wbuf, 3145728);
  conv_cast<<<8192, 256, 0, stream>>>(x, conv_w, xcy);
  gemm2p<8, 4, 1><<<384, 512, 0, stream>>>(xcy, wbuf, nullptr, 4096, 6144, 2048,
                                           ctab, stab, qb, kb, vt);
  cast_bf<<<4096, 256, 0, stream>>>(w_proj, wbuf, 1048576);
  attn_fwd<<<dim3(32, 32), 256, 0, stream>>>(qb, kb, vt, xcy);
  gemm2p<4, 4, 0><<<256, 512, 0, stream>>>(xcy, wbuf, (void*)out, 4096, 2048, 2048,
                                           nullptr, nullptr, nullptr, nullptr, nullptr);
}

// Round 17
// 278.113 us; speedup vs baseline: 1.0210x; 1.0210x over previous
//
#include <hip/hip_runtime.h>

typedef __attribute__((ext_vector_type(8))) short bf16x8;
typedef __attribute__((ext_vector_type(4))) float f32x4;
typedef __attribute__((ext_vector_type(4))) unsigned short u16x4;

#define DEV static __device__ __forceinline__

DEV float bf2f(unsigned short u) {
  union { unsigned int i; float f; } v; v.i = ((unsigned int)u) << 16; return v.f;
}
DEV unsigned short f2bf(float f) {
  unsigned int x = __float_as_uint(f);
  x += 0x7fffu + ((x >> 16) & 1u);   // round-to-nearest-even
  return (unsigned short)(x >> 16);
}
DEV f32x4 mfma16(bf16x8 a, bf16x8 b, f32x4 c) {
  return __builtin_amdgcn_mfma_f32_16x16x32_bf16(a, b, c, 0, 0, 0);
}
DEV void gload_lds16(const void* g, void* l) {
  __builtin_amdgcn_global_load_lds(
      (const __attribute__((address_space(1))) unsigned int*)g,
      (__attribute__((address_space(3))) unsigned int*)l, 16, 0, 0);
}

// ---------------------------------------------------------------- tables
__global__ void build_tables(float* __restrict__ ct, float* __restrict__ st) {
  int idx = blockIdx.x * 256 + threadIdx.x;   // 2048*64 = 131072
  int i = idx & 63, t = idx >> 6;
  float f = powf(10000.0f, -(float)i * (1.0f / 64.0f));
  float a = (float)t * f;
  ct[idx] = cosf(a);
  st[idx] = sinf(a);
}

// ---------------------------------------------------------------- f32 -> bf16 cast (x4)
__global__ void cast_bf(const float* __restrict__ in, unsigned short* __restrict__ out, int n4) {
  int idx = blockIdx.x * 256 + threadIdx.x;
  if (idx >= n4) return;
  f32x4 v = *(const f32x4*)(in + (size_t)idx * 4);
  u16x4 o;
  #pragma unroll
  for (int j = 0; j < 4; ++j) o[j] = f2bf(v[j]);
  *(u16x4*)(out + (size_t)idx * 4) = o;
}

// ---------------------------------------------------------------- depthwise causal conv (K=3) + cast
__global__ void conv_cast(const float* __restrict__ x, const float* __restrict__ w,
                          unsigned short* __restrict__ out) {
  int idx = blockIdx.x * 256 + threadIdx.x;   // B*T*C/4 = 2,097,152
  int c4 = idx & 511, t = (idx >> 9) & 2047;  // b = idx >> 20
  int c = c4 * 4;
  const float* xp = x + (size_t)(idx >> 20) * 2048 * 2048 + (size_t)t * 2048 + c;
  f32x4 v2 = *(const f32x4*)xp;
  f32x4 v1 = {0.f, 0.f, 0.f, 0.f}, v0 = {0.f, 0.f, 0.f, 0.f};
  if (t >= 1) v1 = *(const f32x4*)(xp - 2048);
  if (t >= 2) v0 = *(const f32x4*)(xp - 4096);
  u16x4 o;
  #pragma unroll
  for (int j = 0; j < 4; ++j) {
    float val = v0[j] * w[(c + j) * 3 + 0] + v1[j] * w[(c + j) * 3 + 1] + v2[j] * w[(c + j) * 3 + 2];
    o[j] = f2bf(val);
  }
  *(u16x4*)(idx * 4 + out) = o;
}

// ---------------------------------------------------------------- BT GEMM, 2-phase + counted vmcnt (r6 loop)
// MODE 0: plain f32 C output (proj). MODE 1: fused RoPE(Q,K)+V-transpose epilogue
// (qkv GEMM) — the 256x256 tile covers 2 heads of one q/k/v section; acc is bounced
// through the (now free) 128KB staging LDS as a chunk-swizzled bf16 tile, RoPE pairs
// are col^64 within the tile, outputs written directly to Qo/Ko/Vt.
template <int MFRAG, int NFRAG, int MODE>   // BM=MFRAG*32, BN=NFRAG*64
__global__ __launch_bounds__(512, 2) void gemm2p(const unsigned short* __restrict__ A,
                                                 const unsigned short* __restrict__ Bw,
                                                 void* __restrict__ Cp, int M, int N, int K,
                                                 const float* __restrict__ ct,
                                                 const float* __restrict__ st,
                                                 unsigned short* __restrict__ Qo,
                                                 unsigned short* __restrict__ Ko,
                                                 unsigned short* __restrict__ Vt) {
  constexpr int BM = MFRAG * 32;
  constexpr int BN = NFRAG * 64;
  constexpr int ALD = BM / 128;
  constexpr int BLD = BN / 128;
  constexpr int STEADY = 2 * (ALD + BLD);
  constexpr int HALF = ALD + BLD;
  __shared__ __align__(16) unsigned short smem[2 * 2 * (BM + BN) * 32];
  unsigned short* AsB = smem;                       // [2buf][2kh][BM*32]
  unsigned short* BsB = smem + 2 * 2 * BM * 32;     // [2buf][2kh][BN*32]
  const int tid = threadIdx.x;
  const int w = tid >> 6, l = tid & 63;
  const int lr = l & 15, lg = l >> 4;
  const int wm = w >> 2, wn = w & 3;
  const int nbx = N / BN, nby = M / BM;
  const int nwg = nbx * nby;
  const int bid = blockIdx.x;
  const int wg = (bid & 7) * (nwg >> 3) + (bid >> 3);
  const int bx = wg / nby, by = wg % nby;
  const int m0 = by * BM, n0 = bx * BN;

  int aOff[ALD], bOff[BLD];
  #pragma unroll
  for (int it = 0; it < ALD; ++it) {
    int q = it * 512 + tid, row = q >> 2, cp = q & 3;
    aOff[it] = (m0 + row) * K + ((cp ^ ((row >> 1) & 3)) * 8);
  }
  #pragma unroll
  for (int it = 0; it < BLD; ++it) {
    int q = it * 512 + tid, row = q >> 2, cp = q & 3;
    bOff[it] = (n0 + row) * K + ((cp ^ ((row >> 1) & 3)) * 8);
  }
  const int dstW = w * 512;

  int aRd[MFRAG], bRd[NFRAG];
  #pragma unroll
  for (int m = 0; m < MFRAG; ++m) {
    int R = wm * (MFRAG * 16) + m * 16 + lr;
    aRd[m] = R * 32 + ((lg ^ ((R >> 1) & 3)) * 8);
  }
  #pragma unroll
  for (int n = 0; n < NFRAG; ++n) {
    int R = wn * (NFRAG * 16) + n * 16 + lr;
    bRd[n] = R * 32 + ((lg ^ ((R >> 1) & 3)) * 8);
  }

  auto stageA = [&](int tt, int kh) {
    const unsigned short* s = A + (size_t)(tt * 64 + kh * 32);
    unsigned short* d = AsB + ((tt & 1) * 2 + kh) * (BM * 32) + dstW;
    #pragma unroll
    for (int it = 0; it < ALD; ++it) gload_lds16(s + aOff[it], d + it * 4096);
  };
  auto stageB = [&](int tt, int kh) {
    const unsigned short* s = Bw + (size_t)(tt * 64 + kh * 32);
    unsigned short* d = BsB + ((tt & 1) * 2 + kh) * (BN * 32) + dstW;
    #pragma unroll
    for (int it = 0; it < BLD; ++it) gload_lds16(s + bOff[it], d + it * 4096);
  };
  #define WAIT_STEADY do { if constexpr (STEADY == 8) asm volatile("s_waitcnt vmcnt(8)" ::: "memory"); \
                           else asm volatile("s_waitcnt vmcnt(6)" ::: "memory"); } while (0)
  #define WAIT_HALF   do { if constexpr (HALF == 4) asm volatile("s_waitcnt vmcnt(4)" ::: "memory"); \
                           else asm volatile("s_waitcnt vmcnt(3)" ::: "memory"); } while (0)
  #define WAIT_ZERO   asm volatile("s_waitcnt vmcnt(0)" ::: "memory")

  #define PH(BUF, KH, STAGE_STMT, WAIT_STMT)                              \
  {                                                                       \
    const unsigned short* Ab = AsB + ((BUF) * 2 + (KH)) * (BM * 32);      \
    const unsigned short* Bb = BsB + ((BUF) * 2 + (KH)) * (BN * 32);      \
    bf16x8 aF[MFRAG], bF[NFRAG];                                          \
    _Pragma("unroll") for (int m = 0; m < MFRAG; ++m)                     \
        aF[m] = *(const bf16x8*)(Ab + aRd[m]);                            \
    _Pragma("unroll") for (int n = 0; n < NFRAG; ++n)                     \
        bF[n] = *(const bf16x8*)(Bb + bRd[n]);                            \
    STAGE_STMT;                                                           \
    __builtin_amdgcn_sched_barrier(0);                                    \
    __builtin_amdgcn_s_barrier();                                         \
    __builtin_amdgcn_sched_barrier(0);                                    \
    __builtin_amdgcn_s_setprio(1);                                        \
    _Pragma("unroll") for (int m = 0; m < MFRAG; ++m)                     \
      _Pragma("unroll") for (int n = 0; n < NFRAG; ++n)                   \
          acc[m][n] = mfma16(aF[m], bF[n], acc[m][n]);                    \
    __builtin_amdgcn_s_setprio(0);                                        \
    WAIT_STMT;                                                            \
    __builtin_amdgcn_sched_barrier(0);                                    \
    __builtin_amdgcn_s_barrier();                                         \
    __builtin_amdgcn_sched_barrier(0);                                    \
  }

  f32x4 acc[MFRAG][NFRAG] = {};
  const int NT = K >> 6;
  stageA(0, 0); stageB(0, 0);
  stageA(0, 1); stageB(0, 1);
  stageA(1, 0); stageB(1, 0);
  __builtin_amdgcn_sched_barrier(0);
  WAIT_STEADY;
  __builtin_amdgcn_s_barrier();
  __builtin_amdgcn_sched_barrier(0);

  int t = 0;
  for (; t + 2 < NT; ++t) {
    PH(t & 1, 0, { stageA(t + 1, 1); stageB(t + 1, 1); }, WAIT_STEADY);
    PH(t & 1, 1, { stageA(t + 2, 0); stageB(t + 2, 0); }, WAIT_STEADY);
  }
  PH(t & 1, 0, { stageA(t + 1, 1); stageB(t + 1, 1); }, WAIT_STEADY);
  PH(t & 1, 1, {}, WAIT_HALF);
  ++t;
  PH(t & 1, 0, {}, WAIT_ZERO);
  PH(t & 1, 1, {}, {});
  #undef PH
  #undef WAIT_STEADY
  #undef WAIT_HALF
  #undef WAIT_ZERO

  if constexpr (MODE == 0) {
    // plain f32 epilogue (proj)
    #pragma unroll
    for (int m = 0; m < MFRAG; ++m)
      #pragma unroll
      for (int r = 0; r < 4; ++r) {
        int row = m0 + wm * (MFRAG * 16) + m * 16 + lg * 4 + r;
        #pragma unroll
        for (int n = 0; n < NFRAG; ++n) {
          int col = n0 + wn * (NFRAG * 16) + n * 16 + lr;
          ((float*)Cp)[(size_t)row * N + col] = acc[m][n][r];
        }
      }
  } else {
    // fused RoPE + V-transpose epilogue. 256x256 tile == full staging LDS.
    static_assert(MODE != 1 || (BM == 256 && BN == 256), "fused epilogue needs 256x256");
    auto tadr = [&](int row, int col) {
      return row * 256 + ((((col >> 3) ^ (row & 7))) << 3) + (col & 7);
    };
    // acc -> swizzled bf16 tile (staging reads all completed: final PH ended with barrier)
    #pragma unroll
    for (int m = 0; m < MFRAG; ++m)
      #pragma unroll
      for (int r = 0; r < 4; ++r) {
        int row = wm * (MFRAG * 16) + m * 16 + lg * 4 + r;
        #pragma unroll
        for (int n = 0; n < NFRAG; ++n) {
          int col = wn * (NFRAG * 16) + n * 16 + lr;
          smem[tadr(row, col)] = f2bf(acc[m][n][r]);
        }
      }
    __syncthreads();
    const int sec = n0 >> 11;              // 0=q, 1=k, 2=v
    const int hbase = (n0 & 2047) >> 7;    // head base (2 heads per tile)
    const int bb = m0 >> 11;               // batch
    const int t0a = m0 & 2047;             // t base
    if (sec < 2) {
      unsigned short* outp = (sec == 0) ? Qo : Ko;
      const int c8 = (tid & 31) * 8;       // col base (mult of 8)
      const int rb = tid >> 5;             // 0..15
      const int dloc = c8 & 127;           // d base within head
      const int hh = hbase + (c8 >> 7);
      const bool lowh = dloc < 64;
      const int ib = dloc & 63;
      unsigned short* obase = outp + ((size_t)(bb * 16 + hh) * 2048) * 128;
      #pragma unroll
      for (int j = 0; j < 16; ++j) {
        int row = rb * 16 + j;
        int tt2 = t0a + row;
        bf16x8 self = *(const bf16x8*)(smem + tadr(row, c8));
        bf16x8 part = *(const bf16x8*)(smem + tadr(row, c8 ^ 64));
        const float* cp2 = ct + tt2 * 64 + ib;
        const float* sp2 = st + tt2 * 64 + ib;
        bf16x8 o8;
        #pragma unroll
        for (int e = 0; e < 8; ++e) {
          float a = bf2f(((const unsigned short*)&self)[e]);
          float p = bf2f(((const unsigned short*)&part)[e]);
          float cz = cp2[e], sz = sp2[e];
          ((unsigned short*)&o8)[e] = f2bf(lowh ? (a * cz - p * sz) : (a * cz + p * sz));
        }
        *(bf16x8*)(obase + (size_t)tt2 * 128 + dloc) = o8;
      }
    } else {
      const int c = tid >> 1, half = tid & 1;
      const int dd = c & 127, hh = hbase + (c >> 7);
      unsigned short* dst = Vt + ((size_t)(bb * 16 + hh) * 128 + dd) * 2048 + t0a + half * 128;
      #pragma unroll
      for (int j = 0; j < 16; ++j) {
        bf16x8 v8;
        #pragma unroll
        for (int e = 0; e < 8; ++e)
          ((unsigned short*)&v8)[e] = smem[tadr(half * 128 + j * 8 + e, c)];
        *(bf16x8*)(dst + j * 8) = v8;
      }
    }
  }
}

// ---------------------------------------------------------------- flash attention (causal), swapped QK^T (r14 form)
// defer-max, spill-free: ONE shared exp2 loop; guard wraps only the rescale block.
// grid: (32 bh, 32 qtile) ; block 256 = 4 waves x 16 q-rows ; KV tile 64
__global__ __launch_bounds__(256, 4) void attn_fwd(const unsigned short* __restrict__ Q,
                                                   const unsigned short* __restrict__ K,
                                                   const unsigned short* __restrict__ Vt,
                                                   unsigned short* __restrict__ Y) {
  const int T = 2048, D = 128, C = 2048;
  __shared__ __align__(16) unsigned short Ks[64 * 128];   // [kv][cc ^ (kv&7)]
  __shared__ __align__(16) unsigned short Vs[128 * 64];   // [d][cc ^ (d&7)]
  __shared__ __align__(16) unsigned short Pl[4][16 * 64]; // per-wave [q][cc ^ (q&7)]
  const int tid = threadIdx.x;
  const int w = tid >> 6, l = tid & 63;
  const int lr = l & 15, lg = l >> 4;
  const int bh = blockIdx.x;
  const int qi = (int)gridDim.y - 1 - (int)blockIdx.y;    // longest-first
  const int qbase = qi * 64;
  const size_t base = (size_t)bh * T * D;

  bf16x8 qf[4];
  {
    const unsigned short* qp = Q + base + (size_t)(qbase + w * 16 + lr) * D + lg * 8;
    #pragma unroll
    for (int d = 0; d < 4; ++d) qf[d] = *(const bf16x8*)(qp + d * 32);
  }
  int kSrc[4], vSrc[4], ldsDst[4];
  #pragma unroll
  for (int it = 0; it < 4; ++it) {
    int c = it * 256 + tid;
    int krow = c >> 4, kdc = c & 15;
    kSrc[it] = krow * D + ((kdc ^ (krow & 7)) * 8);
    int vd = c >> 3, vcc = c & 7;
    vSrc[it] = vd * T + ((vcc ^ (vd & 7)) * 8);
    ldsDst[it] = (it * 256 + w * 64) * 8;
  }
  f32x4 ao[8] = {};
  float mrun = -3.0e38f, lrun = 0.0f;
  const float cs = 0.08838834764831845f * 1.4426950408889634f;  // 1/sqrt(128) * log2(e)
  const float THR = 8.0f / cs;                                  // growth bound: p <= 2^8
  const int q_abs = qbase + w * 16 + lr;

  for (int kt = 0; kt <= qi; ++kt) {
    const int kv0 = kt * 64;
    #pragma unroll
    for (int it = 0; it < 4; ++it) {
      gload_lds16(K + base + (size_t)kv0 * D + kSrc[it], Ks + ldsDst[it]);
      gload_lds16(Vt + base + kv0 + vSrc[it], Vs + ldsDst[it]);
    }
    __syncthreads();
    f32x4 s4[4] = {};
    __builtin_amdgcn_s_setprio(1);
    #pragma unroll
    for (int n = 0; n < 4; ++n) {
      int row = n * 16 + lr;
      #pragma unroll
      for (int d = 0; d < 4; ++d) {
        bf16x8 kf = *(const bf16x8*)(Ks + row * 128 + (((d * 4 + lg) ^ (lr & 7)) * 8));
        s4[n] = mfma16(kf, qf[d], s4[n]);
      }
    }
    __builtin_amdgcn_s_setprio(0);
    if (kt == qi) {
      #pragma unroll
      for (int n = 0; n < 4; ++n)
        #pragma unroll
        for (int r = 0; r < 4; ++r)
          if (kv0 + n * 16 + lg * 4 + r > q_abs) s4[n][r] = -3.0e38f;
    }
    float mx = -3.0e38f;
    #pragma unroll
    for (int n = 0; n < 4; ++n)
      #pragma unroll
      for (int r = 0; r < 4; ++r) mx = fmaxf(mx, s4[n][r]);
    mx = fmaxf(mx, __shfl_xor(mx, 16, 64));
    mx = fmaxf(mx, __shfl_xor(mx, 32, 64));
    if (!__all(mx - mrun <= THR)) {
      float mnew = fmaxf(mrun, mx);
      float fac = exp2f((mrun - mnew) * cs);
      mrun = mnew;
      lrun *= fac;
      float fr[4];
      #pragma unroll
      for (int r = 0; r < 4; ++r) fr[r] = __shfl(fac, (l & 48) | (lg * 4 + r), 64);
      #pragma unroll
      for (int n8 = 0; n8 < 8; ++n8)
        #pragma unroll
        for (int r = 0; r < 4; ++r) ao[n8][r] *= fr[r];
    }
    float sum = 0.0f;
    #pragma unroll
    for (int n = 0; n < 4; ++n)
      #pragma unroll
      for (int r = 0; r < 4; ++r) {
        float p = exp2f((s4[n][r] - mrun) * cs);
        s4[n][r] = p;
        sum += p;
      }
    sum += __shfl_xor(sum, 16, 64);
    sum += __shfl_xor(sum, 32, 64);
    lrun += sum;
    unsigned short* pw = (unsigned short*)Pl[w];
    #pragma unroll
    for (int n = 0; n < 4; ++n)
      #pragma unroll
      for (int i = 0; i < 2; ++i) {
        unsigned int pk = (unsigned int)f2bf(s4[n][2 * i]) |
                          ((unsigned int)f2bf(s4[n][2 * i + 1]) << 16);
        int kv = n * 16 + lg * 4 + 2 * i;
        *(unsigned int*)(pw + lr * 64 + (((kv >> 3) ^ (lr & 7)) * 8) + (kv & 7)) = pk;
      }
    __builtin_amdgcn_s_setprio(1);
    #pragma unroll
    for (int ks = 0; ks < 2; ++ks) {
      bf16x8 pa = *(const bf16x8*)(pw + lr * 64 + (((ks * 4 + lg) ^ (lr & 7)) * 8));
      #pragma unroll
      for (int n = 0; n < 8; ++n) {
        int row = n * 16 + lr;
        bf16x8 vb = *(const bf16x8*)(Vs + row * 64 + (((ks * 4 + lg) ^ (lr & 7)) * 8));
        ao[n] = mfma16(pa, vb, ao[n]);
      }
    }
    __builtin_amdgcn_s_setprio(0);
    __syncthreads();
  }
  const int b = bh >> 4, h = bh & 15;
  #pragma unroll
  for (int r = 0; r < 4; ++r) {
    float lsum = __shfl(lrun, (l & 48) | (lg * 4 + r), 64);
    float inv = 1.0f / lsum;
    int t = qbase + w * 16 + lg * 4 + r;
    unsigned short* dst = Y + ((size_t)b * T + t) * C + h * D;
    #pragma unroll
    for (int n = 0; n < 8; ++n) dst[n * 16 + lr] = f2bf(ao[n][r] * inv);
  }
}

// ---------------------------------------------------------------- launch
extern "C" void kernel_launch(void* const* d_in, const int* in_sizes, int n_in,
                              void* d_out, int out_size, void* d_ws, size_t ws_size,
                              hipStream_t stream) {
  const float* x      = (const float*)d_in[0];
  const float* conv_w = (const float*)d_in[1];
  const float* w_attn = (const float*)d_in[2];
  const float* w_proj = (const float*)d_in[3];
  float* out = (float*)d_out;
  char* ws = (char*)d_ws;

  unsigned short* qb   = (unsigned short*)(ws + 50331648);      // 16,777,216
  unsigned short* kb   = (unsigned short*)(ws + 67108864);      // 16,777,216
  unsigned short* vt   = (unsigned short*)(ws + 83886080);      // 16,777,216 (V transposed)
  unsigned short* xcy  = (unsigned short*)(ws + 100663296);     // 16,777,216 (xconv, then y)
  unsigned short* wbuf = (unsigned short*)(ws + 117440512);     // 25,165,824
  float* ctab = (float*)(ws + 142606336);                       // 524,288
  float* stab = (float*)(ws + 143130624);                       // 524,288

  build_tables<<<512, 256, 0, stream>>>(ctab, stab);
  cast_bf<<<12288, 256, 0, stream>>>(w_attn, wbuf, 3145728);
  conv_cast<<<8192, 256, 0, stream>>>(x, conv_w, xcy);
  gemm2p<8, 4, 1><<<384, 512, 0, stream>>>(xcy, wbuf, nullptr, 4096, 6144, 2048,
                                           ctab, stab, qb, kb, vt);
  cast_bf<<<4096, 256, 0, stream>>>(w_proj, wbuf, 1048576);
  attn_fwd<<<dim3(32, 32), 256, 0, stream>>>(qb, kb, vt, xcy);
  gemm2p<4, 4, 0><<<256, 512, 0, stream>>>(xcy, wbuf, (void*)out, 4096, 2048, 2048,
                                           nullptr, nullptr, nullptr, nullptr, nullptr);
}